// Round 1
// baseline (155.026 us; speedup 1.0000x reference)
//
#include <hip/hip_runtime.h>
#include <hip/hip_bf16.h>

#define NB 64          // number of bins (nb = in_sizes[3]-1; asserted implicitly)
#define NE (NB + 1)    // number of edges

// ---------------------------------------------------------------------------
// Kernel 1: fused dual masked histogram.
// Each block handles a contiguous chunk of one batch. LDS histograms, then
// one global atomicAdd per bin per block.
// counts layout in ws: [0 .. B*NB)        = counts_obs  (uint32)
//                      [B*NB .. 2*B*NB)   = counts_pred (uint32)
// ---------------------------------------------------------------------------
__device__ __forceinline__ int bin_of(float x, const float* __restrict__ e) {
    // numpy searchsorted(e, x, side='right') - 1 ; then rightmost edge -> last bin
    int lo = 0, hi = NE;
    // ceil(log2(65)) = 7 iterations for every lane -> uniform control flow
    while (lo < hi) {
        int mid = (lo + hi) >> 1;
        if (e[mid] <= x) lo = mid + 1; else hi = mid;
    }
    int idx = lo - 1;
    if (x == e[NE - 1]) idx = NB - 1;
    return idx;   // caller checks 0 <= idx < NB
}

__global__ void __launch_bounds__(256)
hist_kernel(const float* __restrict__ obs,
            const float* __restrict__ pred,
            const int*   __restrict__ mask,
            const float* __restrict__ edges,
            unsigned int* __restrict__ counts,   // [2][B][NB]
            int elemsPerBatch, int blocksPerBatch, int B)
{
    __shared__ unsigned int s_obs[NB];
    __shared__ unsigned int s_pred[NB];
    __shared__ float        s_edges[NE];

    const int tid = threadIdx.x;
    if (tid < NB) { s_obs[tid] = 0u; s_pred[tid] = 0u; }
    if (tid < NE) s_edges[tid] = edges[tid];
    __syncthreads();

    const int b     = blockIdx.x / blocksPerBatch;
    const int chunk = blockIdx.x % blocksPerBatch;
    const int perBlock = elemsPerBatch / blocksPerBatch;        // divisible by 1024
    const size_t base  = (size_t)b * (size_t)elemsPerBatch;

    const float4* o4 = reinterpret_cast<const float4*>(obs  + base);
    const float4* p4 = reinterpret_cast<const float4*>(pred + base);
    const int4*   m4 = reinterpret_cast<const int4*>(mask + base);

    const int startV = (chunk * perBlock) >> 2;                 // in float4 units
    const int endV   = startV + (perBlock >> 2);

    for (int i = startV + tid; i < endV; i += blockDim.x) {
        float4 o = o4[i];
        float4 p = p4[i];
        int4   m = m4[i];

        {
            int idx = bin_of(o.x, s_edges);
            if (m.x && idx >= 0 && idx < NB) atomicAdd(&s_obs[idx], 1u);
            idx = bin_of(p.x, s_edges);
            if (m.x && idx >= 0 && idx < NB) atomicAdd(&s_pred[idx], 1u);
        }
        {
            int idx = bin_of(o.y, s_edges);
            if (m.y && idx >= 0 && idx < NB) atomicAdd(&s_obs[idx], 1u);
            idx = bin_of(p.y, s_edges);
            if (m.y && idx >= 0 && idx < NB) atomicAdd(&s_pred[idx], 1u);
        }
        {
            int idx = bin_of(o.z, s_edges);
            if (m.z && idx >= 0 && idx < NB) atomicAdd(&s_obs[idx], 1u);
            idx = bin_of(p.z, s_edges);
            if (m.z && idx >= 0 && idx < NB) atomicAdd(&s_pred[idx], 1u);
        }
        {
            int idx = bin_of(o.w, s_edges);
            if (m.w && idx >= 0 && idx < NB) atomicAdd(&s_obs[idx], 1u);
            idx = bin_of(p.w, s_edges);
            if (m.w && idx >= 0 && idx < NB) atomicAdd(&s_pred[idx], 1u);
        }
    }
    __syncthreads();

    if (tid < NB) {
        unsigned int co = s_obs[tid];
        unsigned int cp = s_pred[tid];
        if (co) atomicAdd(&counts[(size_t)b * NB + tid], co);
        if (cp) atomicAdd(&counts[(size_t)B * NB + (size_t)b * NB + tid], cp);
    }
}

// ---------------------------------------------------------------------------
// Kernel 2: finalize. One wave (64 threads), lane t = bin t. Loops over B.
// out[0] = w2_loss, out[1 .. 1+B*NB) = p_obs, out[1+B*NB .. 1+2*B*NB) = p_pred
// ---------------------------------------------------------------------------
__device__ __forceinline__ float wave_sum64(float v) {
    for (int o = 32; o > 0; o >>= 1) v += __shfl_xor(v, o, 64);
    return v;
}
__device__ __forceinline__ float wave_incl_scan64(float v, int lane) {
    for (int d = 1; d < 64; d <<= 1) {
        float u = __shfl_up(v, d, 64);
        if (lane >= d) v += u;
    }
    return v;
}

__global__ void __launch_bounds__(64)
finalize_kernel(const unsigned int* __restrict__ counts,  // [2][B][NB]
                const float* __restrict__ edges,
                const float* __restrict__ bweights,
                float* __restrict__ out, int B)
{
    const int t = threadIdx.x;    // 0..63 == bin index

    // bin widths exactly as reference computes them:
    // mid(i) = 0.5*(e[i]+e[i+1]); width[t] = t<NB-1 ? mid(t+1)-mid(t) : mid(NB-1)-mid(NB-2)
    float midA = 0.5f * (edges[t] + edges[t + 1]);
    float width;
    if (t < NB - 1) {
        float midB = 0.5f * (edges[t + 1] + edges[t + 2]);
        width = midB - midA;
    } else {
        float midPrev = 0.5f * (edges[NB - 2] + edges[NB - 1]);
        width = midA - midPrev;
    }
    const float bw = bweights[t];

    float loss_acc = 0.0f;
    for (int b = 0; b < B; ++b) {
        float co = (float)counts[(size_t)b * NB + t];
        float cp = (float)counts[(size_t)B * NB + (size_t)b * NB + t];

        float to = wave_sum64(co);
        if (to == 0.0f) { co = 1.0f; to = 64.0f; }
        float tp = wave_sum64(cp);
        if (tp == 0.0f) { cp = 1.0f; tp = 64.0f; }

        float po = co / to;
        float pp = cp / tp;
        out[1 + (size_t)b * NB + t]                    = po;
        out[1 + (size_t)B * NB + (size_t)b * NB + t]   = pp;

        float cdfo = wave_incl_scan64(po, t);
        float cdfp = wave_incl_scan64(pp, t);
        float d = cdfo - cdfp;
        float wd = d * d * width * bw;
        float s = wave_sum64(wd);
        if (t == 0) loss_acc += s;
    }
    if (t == 0) out[0] = loss_acc / (float)B;
}

// ---------------------------------------------------------------------------
extern "C" void kernel_launch(void* const* d_in, const int* in_sizes, int n_in,
                              void* d_out, int out_size, void* d_ws, size_t ws_size,
                              hipStream_t stream) {
    const float* obs      = (const float*)d_in[0];
    const float* pred     = (const float*)d_in[1];
    const int*   mask     = (const int*)d_in[2];
    const float* edges    = (const float*)d_in[3];
    const float* bweights = (const float*)d_in[4];
    float* out = (float*)d_out;

    const int nb = in_sizes[3] - 1;                 // 64
    const int B  = (out_size - 1) / (2 * nb);       // 32
    const int elemsPerBatch = in_sizes[0] / B;      // 1048576

    unsigned int* counts = (unsigned int*)d_ws;     // [2][B][nb] uint32
    const size_t countsBytes = (size_t)2 * B * nb * sizeof(unsigned int);

    hipMemsetAsync(d_ws, 0, countsBytes, stream);

    const int blocksPerBatch = 64;                  // 16384 elems / block
    dim3 grid(B * blocksPerBatch), block(256);
    hist_kernel<<<grid, block, 0, stream>>>(obs, pred, mask, edges, counts,
                                            elemsPerBatch, blocksPerBatch, B);

    finalize_kernel<<<1, 64, 0, stream>>>(counts, edges, bweights, out, B);
}

// Round 2
// 117.642 us; speedup vs baseline: 1.3178x; 1.3178x over previous
//
#include <hip/hip_runtime.h>
#include <hip/hip_bf16.h>

#define NB 64          // number of bins
#define NE (NB + 1)    // number of edges
#define R  16          // histogram replication factor (power of 2)

// ---------------------------------------------------------------------------
// Exact searchsorted(side='right')-1 semantics via uniform guess + fixup.
// Returns -1 for dropped values (out of range, NaN). Right-most edge -> NB-1.
// Fixup loops compare against the ACTUAL edge floats, so result is bit-exact
// for any sorted edges; for linspace edges they run 0-1 iterations.
// ---------------------------------------------------------------------------
__device__ __forceinline__ int bin_of_fast(float x, const float* __restrict__ e,
                                           float e0, float eN, float invstep) {
    if (!(x >= e0) || !(x <= eN)) return -1;   // drops NaN too
    if (x == eN) return NB - 1;                // rightmost edge belongs to last bin
    int g = (int)((x - e0) * invstep);
    g = min(max(g, 0), NB - 1);
    while (e[g] > x) --g;                      // e[0] = e0 <= x guarantees stop
    while (e[g + 1] <= x) ++g;                 // x < e[NB] guarantees stop
    return g;
}

// ---------------------------------------------------------------------------
// Kernel 1: fused dual masked histogram with 16x replicated LDS histograms.
// Layout [R][NE] (stride 65 words): bank(r,b) = (r + b) % 32 -> one bin is
// spread across 16 banks/addresses -> minimal atomic serialization.
// counts layout in ws: [0 .. B*NB) = obs, [B*NB .. 2*B*NB) = pred (uint32)
// ---------------------------------------------------------------------------
__global__ void __launch_bounds__(256)
hist_kernel(const float* __restrict__ obs,
            const float* __restrict__ pred,
            const int*   __restrict__ mask,
            const float* __restrict__ edges,
            unsigned int* __restrict__ counts,
            int elemsPerBatch, int blocksPerBatch, int B)
{
    __shared__ float        s_edges[NE];
    __shared__ unsigned int s_obs[R][NE];
    __shared__ unsigned int s_pred[R][NE];

    const int tid = threadIdx.x;
    for (int i = tid; i < R * NE; i += blockDim.x) {
        (&s_obs[0][0])[i]  = 0u;
        (&s_pred[0][0])[i] = 0u;
    }
    if (tid < NE) s_edges[tid] = edges[tid];
    __syncthreads();

    const float e0 = s_edges[0];
    const float eN = s_edges[NB];
    const float invstep = (float)NB / (eN - e0);

    const int b     = blockIdx.x / blocksPerBatch;
    const int chunk = blockIdx.x % blocksPerBatch;
    const int perBlock = elemsPerBatch / blocksPerBatch;
    const size_t base  = (size_t)b * (size_t)elemsPerBatch;

    const float4* o4 = reinterpret_cast<const float4*>(obs  + base);
    const float4* p4 = reinterpret_cast<const float4*>(pred + base);
    const int4*   m4 = reinterpret_cast<const int4*>(mask + base);

    const int startV = (chunk * perBlock) >> 2;
    const int endV   = startV + (perBlock >> 2);
    const int c = tid & (R - 1);

    for (int i = startV + tid; i < endV; i += blockDim.x) {
        float4 o = o4[i];
        float4 p = p4[i];
        int4   m = m4[i];

        if (m.x) {
            int io = bin_of_fast(o.x, s_edges, e0, eN, invstep);
            if (io >= 0) atomicAdd(&s_obs[c][io], 1u);
            int ip = bin_of_fast(p.x, s_edges, e0, eN, invstep);
            if (ip >= 0) atomicAdd(&s_pred[c][ip], 1u);
        }
        if (m.y) {
            int io = bin_of_fast(o.y, s_edges, e0, eN, invstep);
            if (io >= 0) atomicAdd(&s_obs[c][io], 1u);
            int ip = bin_of_fast(p.y, s_edges, e0, eN, invstep);
            if (ip >= 0) atomicAdd(&s_pred[c][ip], 1u);
        }
        if (m.z) {
            int io = bin_of_fast(o.z, s_edges, e0, eN, invstep);
            if (io >= 0) atomicAdd(&s_obs[c][io], 1u);
            int ip = bin_of_fast(p.z, s_edges, e0, eN, invstep);
            if (ip >= 0) atomicAdd(&s_pred[c][ip], 1u);
        }
        if (m.w) {
            int io = bin_of_fast(o.w, s_edges, e0, eN, invstep);
            if (io >= 0) atomicAdd(&s_obs[c][io], 1u);
            int ip = bin_of_fast(p.w, s_edges, e0, eN, invstep);
            if (ip >= 0) atomicAdd(&s_pred[c][ip], 1u);
        }
    }
    __syncthreads();

    if (tid < NB) {
        unsigned int so = 0u, sp = 0u;
        #pragma unroll
        for (int r = 0; r < R; ++r) { so += s_obs[r][tid]; sp += s_pred[r][tid]; }
        if (so) atomicAdd(&counts[(size_t)b * NB + tid], so);
        if (sp) atomicAdd(&counts[(size_t)B * NB + (size_t)b * NB + tid], sp);
    }
}

// ---------------------------------------------------------------------------
// Kernel 2: finalize. One wave, lane t = bin t.
// out[0] = w2_loss, out[1 .. 1+B*NB) = p_obs, out[1+B*NB ..) = p_pred
// ---------------------------------------------------------------------------
__device__ __forceinline__ float wave_sum64(float v) {
    for (int o = 32; o > 0; o >>= 1) v += __shfl_xor(v, o, 64);
    return v;
}
__device__ __forceinline__ float wave_incl_scan64(float v, int lane) {
    for (int d = 1; d < 64; d <<= 1) {
        float u = __shfl_up(v, d, 64);
        if (lane >= d) v += u;
    }
    return v;
}

__global__ void __launch_bounds__(64)
finalize_kernel(const unsigned int* __restrict__ counts,
                const float* __restrict__ edges,
                const float* __restrict__ bweights,
                float* __restrict__ out, int B)
{
    const int t = threadIdx.x;    // 0..63 == bin index

    float midA = 0.5f * (edges[t] + edges[t + 1]);
    float width;
    if (t < NB - 1) {
        float midB = 0.5f * (edges[t + 1] + edges[t + 2]);
        width = midB - midA;
    } else {
        float midPrev = 0.5f * (edges[NB - 2] + edges[NB - 1]);
        width = midA - midPrev;
    }
    const float bw = bweights[t];

    float loss_acc = 0.0f;
    for (int b = 0; b < B; ++b) {
        float co = (float)counts[(size_t)b * NB + t];
        float cp = (float)counts[(size_t)B * NB + (size_t)b * NB + t];

        float to = wave_sum64(co);
        if (to == 0.0f) { co = 1.0f; to = 64.0f; }
        float tp = wave_sum64(cp);
        if (tp == 0.0f) { cp = 1.0f; tp = 64.0f; }

        float po = co / to;
        float pp = cp / tp;
        out[1 + (size_t)b * NB + t]                  = po;
        out[1 + (size_t)B * NB + (size_t)b * NB + t] = pp;

        float cdfo = wave_incl_scan64(po, t);
        float cdfp = wave_incl_scan64(pp, t);
        float d = cdfo - cdfp;
        float wd = d * d * width * bw;
        float s = wave_sum64(wd);
        if (t == 0) loss_acc += s;
    }
    if (t == 0) out[0] = loss_acc / (float)B;
}

// ---------------------------------------------------------------------------
extern "C" void kernel_launch(void* const* d_in, const int* in_sizes, int n_in,
                              void* d_out, int out_size, void* d_ws, size_t ws_size,
                              hipStream_t stream) {
    const float* obs      = (const float*)d_in[0];
    const float* pred     = (const float*)d_in[1];
    const int*   mask     = (const int*)d_in[2];
    const float* edges    = (const float*)d_in[3];
    const float* bweights = (const float*)d_in[4];
    float* out = (float*)d_out;

    const int nb = in_sizes[3] - 1;                 // 64
    const int B  = (out_size - 1) / (2 * nb);       // 32
    const int elemsPerBatch = in_sizes[0] / B;      // 1048576

    unsigned int* counts = (unsigned int*)d_ws;     // [2][B][nb] uint32
    const size_t countsBytes = (size_t)2 * B * nb * sizeof(unsigned int);

    hipMemsetAsync(d_ws, 0, countsBytes, stream);

    const int blocksPerBatch = 64;                  // 16384 elems / block
    dim3 grid(B * blocksPerBatch), block(256);
    hist_kernel<<<grid, block, 0, stream>>>(obs, pred, mask, edges, counts,
                                            elemsPerBatch, blocksPerBatch, B);

    finalize_kernel<<<1, 64, 0, stream>>>(counts, edges, bweights, out, B);
}